// Round 1
// baseline (275.928 us; speedup 1.0000x reference)
//
#include <hip/hip_runtime.h>
#include <hip/hip_bf16.h>

// Problem: B=2048, IN_DIM=1024, HID=512, FEAT=256, all fp32.
//   h_b = relu(x_b @ W_feat + b_feat)          [2048,512]   (b = 0,1)
//   f_b = h_b @ W_br_b + b_br_b                [2048,256]
//   out[b,c] = sum_{j,i} f1[j] f0[i] W_out[j*256+i, c] + b_out[c]
// Kron trick: view W_out as Wr[256, 512] (row j, col i*2+c):
//   t = f1 @ Wr                                 [2048,512]
//   out[b,c] = sum_i f0[b,i] * t[b, i*2+c] + b_out[c]

#define BM 64
#define BN 64
#define BK 16

// C = [relu](A @ W + bias); A: MxK row-major, W: KxN row-major, C: MxN.
// blockIdx.z selects the (A,W,bias,C) pointer set (two branches per launch).
// Requires M%64==0, N%64==0, K%16==0 (true for all three uses).
__global__ __launch_bounds__(256) void gemm_k(
    const float* __restrict__ A0, const float* __restrict__ A1,
    const float* __restrict__ W0, const float* __restrict__ W1,
    const float* __restrict__ bias0, const float* __restrict__ bias1,
    float* __restrict__ C0, float* __restrict__ C1,
    int M, int N, int K, int relu)
{
    const float* A    = blockIdx.z ? A1 : A0;
    const float* W    = blockIdx.z ? W1 : W0;
    const float* bias = blockIdx.z ? bias1 : bias0;
    float*       C    = blockIdx.z ? C1 : C0;

    __shared__ float As[BK][BM + 1];
    __shared__ float Ws[BK][BN + 1];

    const int tid = threadIdx.x;
    const int tx  = tid & 15;   // 0..15 -> 4 output cols each
    const int ty  = tid >> 4;   // 0..15 -> 4 output rows each
    const int bm  = blockIdx.y * BM;
    const int bn  = blockIdx.x * BN;

    float acc[4][4] = {};

    for (int kk = 0; kk < K; kk += BK) {
        // A tile: 64(m) x 16(k), stored transposed As[k][m]
        #pragma unroll
        for (int i = 0; i < 4; ++i) {
            int e = tid + i * 256;
            int m = e >> 4;
            int k = e & 15;
            As[k][m] = A[(size_t)(bm + m) * K + kk + k];
        }
        // W tile: 16(k) x 64(n)
        #pragma unroll
        for (int i = 0; i < 4; ++i) {
            int e = tid + i * 256;
            int k = e >> 6;
            int n = e & 63;
            Ws[k][n] = W[(size_t)(kk + k) * N + bn + n];
        }
        __syncthreads();

        #pragma unroll
        for (int k = 0; k < BK; ++k) {
            float a[4], w[4];
            #pragma unroll
            for (int i = 0; i < 4; ++i) a[i] = As[k][ty * 4 + i];
            #pragma unroll
            for (int j = 0; j < 4; ++j) w[j] = Ws[k][tx * 4 + j];
            #pragma unroll
            for (int i = 0; i < 4; ++i)
                #pragma unroll
                for (int j = 0; j < 4; ++j)
                    acc[i][j] = fmaf(a[i], w[j], acc[i][j]);
        }
        __syncthreads();
    }

    #pragma unroll
    for (int i = 0; i < 4; ++i) {
        int m = bm + ty * 4 + i;
        #pragma unroll
        for (int j = 0; j < 4; ++j) {
            int n = bn + tx * 4 + j;
            float v = acc[i][j] + (bias ? bias[n] : 0.0f);
            if (relu) v = fmaxf(v, 0.0f);
            C[(size_t)m * N + n] = v;
        }
    }
}

// out[b,c] = sum_i f0[b,i] * t[b, i*2+c] + b_out[c]; one block per row b.
__global__ __launch_bounds__(256) void kron_reduce(
    const float* __restrict__ f0, const float* __restrict__ t,
    const float* __restrict__ b_out, float* __restrict__ out)
{
    const int b = blockIdx.x;
    const int i = threadIdx.x;             // 0..255
    const float  v  = f0[(size_t)b * 256 + i];
    const float2 tv = ((const float2*)(t + (size_t)b * 512))[i];
    float p0 = v * tv.x;
    float p1 = v * tv.y;

    #pragma unroll
    for (int off = 32; off > 0; off >>= 1) {
        p0 += __shfl_down(p0, off);
        p1 += __shfl_down(p1, off);
    }
    __shared__ float s0[4], s1[4];
    const int wave = i >> 6;
    if ((i & 63) == 0) { s0[wave] = p0; s1[wave] = p1; }
    __syncthreads();
    if (i == 0) {
        out[(size_t)b * 2 + 0] = s0[0] + s0[1] + s0[2] + s0[3] + b_out[0];
        out[(size_t)b * 2 + 1] = s1[0] + s1[1] + s1[2] + s1[3] + b_out[1];
    }
}

extern "C" void kernel_launch(void* const* d_in, const int* in_sizes, int n_in,
                              void* d_out, int out_size, void* d_ws, size_t ws_size,
                              hipStream_t stream) {
    const float* x0     = (const float*)d_in[0];
    const float* x1     = (const float*)d_in[1];
    const float* W_feat = (const float*)d_in[2];
    const float* b_feat = (const float*)d_in[3];
    const float* W_br0  = (const float*)d_in[4];
    const float* b_br0  = (const float*)d_in[5];
    const float* W_br1  = (const float*)d_in[6];
    const float* b_br1  = (const float*)d_in[7];
    const float* W_out  = (const float*)d_in[8];
    const float* b_out  = (const float*)d_in[9];
    float* out = (float*)d_out;

    const int B = 2048, HID = 512, FEAT = 256;

    float* ws = (float*)d_ws;
    float* h0 = ws;                       // 2048*512
    float* h1 = h0 + (size_t)B * HID;     // 2048*512
    float* f0 = h1 + (size_t)B * HID;     // 2048*256
    float* f1 = f0 + (size_t)B * FEAT;    // 2048*256
    float* t  = f1 + (size_t)B * FEAT;    // 2048*512
    // total: 16 MiB of d_ws

    dim3 blk(256);

    // h_b = relu(x_b @ W_feat + b_feat)   [2048,512], K=1024
    gemm_k<<<dim3(512 / BN, B / BM, 2), blk, 0, stream>>>(
        x0, x1, W_feat, W_feat, b_feat, b_feat, h0, h1, B, 512, 1024, 1);

    // f_b = h_b @ W_br_b + b_br_b         [2048,256], K=512
    gemm_k<<<dim3(256 / BN, B / BM, 2), blk, 0, stream>>>(
        h0, h1, W_br0, W_br1, b_br0, b_br1, f0, f1, B, 256, 512, 0);

    // t = f1 @ Wr (W_out viewed as [256,512] row-major)  K=256
    gemm_k<<<dim3(512 / BN, B / BM, 1), blk, 0, stream>>>(
        f1, f1, W_out, W_out, nullptr, nullptr, t, t, B, 512, 256, 0);

    // out[b,c] = sum_i f0[b,i]*t[b,i*2+c] + b_out[c]
    kron_reduce<<<dim3(B), blk, 0, stream>>>(f0, t, b_out, out);
}

// Round 2
// 156.557 us; speedup vs baseline: 1.7625x; 1.7625x over previous
//
#include <hip/hip_runtime.h>
#include <hip/hip_bf16.h>

// Problem: B=2048, IN_DIM=1024, HID=512, FEAT=256, all fp32.
//   h_b = relu(x_b @ W_feat + b_feat)          [2048,512]   (b = 0,1)
//   f_b = h_b @ W_br_b + b_br_b                [2048,256]
//   out[b,c] = sum_{j,i} f1[j] f0[i] W_out[j*256+i, c] + b_out[c]
// Kron trick: W_out viewed as Wr[256,512] (row j, col i*2+c):
//   t = f1 @ Wr;  out[b,c] = sum_i f0[b,i] * t[b, i*2+c] + b_out[c]
//
// R2: bf16 MFMA GEMM (fp32 in/out, RNE-convert in LDS staging, fp32 accum).

#define BM 64
#define BN 64
#define BK 64
#define LDS_STRIDE 72   // 64 + 8 bf16 pad: row stride 144 B = 36 dwords -> 2-way bank alias (free)

typedef __attribute__((ext_vector_type(8))) short bf16x8;  // 8 bf16 = 4 VGPRs
typedef __attribute__((ext_vector_type(4))) float f32x4;

__device__ __forceinline__ unsigned short f2bf(float f) {
    unsigned int u = __float_as_uint(f);
    unsigned int r = (u + 0x7FFFu + ((u >> 16) & 1u)) >> 16;   // RNE
    return (unsigned short)r;
}

// C = [relu](A @ W + bias); A: MxK fp32 row-major, W: KxN fp32 row-major.
// blockIdx.z picks branch pointer set. Requires M%64==0, N%64==0, K%64==0.
__global__ __launch_bounds__(256) void gemm_mfma(
    const float* __restrict__ A0, const float* __restrict__ A1,
    const float* __restrict__ W0, const float* __restrict__ W1,
    const float* __restrict__ bias0, const float* __restrict__ bias1,
    float* __restrict__ C0, float* __restrict__ C1,
    int M, int N, int K, int relu)
{
    const float* A    = blockIdx.z ? A1 : A0;
    const float* W    = blockIdx.z ? W1 : W0;
    const float* bias = blockIdx.z ? bias1 : bias0;
    float*       C    = blockIdx.z ? C1 : C0;

    __shared__ __align__(16) unsigned short As[BM * LDS_STRIDE]; // [m][k]
    __shared__ __align__(16) unsigned short Wt[BN * LDS_STRIDE]; // [n][k]

    const int tid  = threadIdx.x;
    const int lane = tid & 63;
    const int wave = tid >> 6;          // 0..3
    const int wr   = wave >> 1;         // wave row (0..1) -> 32 rows
    const int wc   = wave & 1;          // wave col (0..1) -> 32 cols
    const int lrow = lane & 15;         // m (A frag) / n (B frag)
    const int quad = lane >> 4;         // 0..3
    const int kq   = quad * 8;

    const int bm = blockIdx.y * BM;
    const int bn = blockIdx.x * BN;

    f32x4 acc[2][2] = {};

    for (int kk = 0; kk < K; kk += BK) {
        // ---- A tile: 64(m) x 64(k) fp32 -> bf16 As[m][k] ----
        #pragma unroll
        for (int i = 0; i < 4; ++i) {
            int idx = i * 256 + tid;            // 0..1023
            int m   = idx >> 4;
            int k4  = (idx & 15) * 4;
            const float4 v = *(const float4*)&A[(size_t)(bm + m) * K + kk + k4];
            ushort4 h;
            h.x = f2bf(v.x); h.y = f2bf(v.y); h.z = f2bf(v.z); h.w = f2bf(v.w);
            *(ushort4*)&As[m * LDS_STRIDE + k4] = h;
        }
        // ---- W tile: 64(k) x 64(n) fp32 -> bf16 Wt[n][k] (transposed) ----
        #pragma unroll
        for (int s = 0; s < 2; ++s) {
            int sb = s * 256 + tid;             // 0..511, 2(k)x4(n) sub-blocks
            int k  = (sb >> 4) * 2;
            int n4 = (sb & 15) * 4;
            const float4 r0 = *(const float4*)&W[(size_t)(kk + k)     * N + bn + n4];
            const float4 r1 = *(const float4*)&W[(size_t)(kk + k + 1) * N + bn + n4];
            const float e0[4] = {r0.x, r0.y, r0.z, r0.w};
            const float e1[4] = {r1.x, r1.y, r1.z, r1.w};
            #pragma unroll
            for (int j = 0; j < 4; ++j) {
                unsigned int p = (unsigned int)f2bf(e0[j]) |
                                 ((unsigned int)f2bf(e1[j]) << 16);
                *(unsigned int*)&Wt[(n4 + j) * LDS_STRIDE + k] = p;
            }
        }
        __syncthreads();

        #pragma unroll
        for (int ks = 0; ks < 2; ++ks) {
            const int k0 = ks * 32 + kq;
            bf16x8 a0 = *(const bf16x8*)&As[(wr * 32 +      lrow) * LDS_STRIDE + k0];
            bf16x8 a1 = *(const bf16x8*)&As[(wr * 32 + 16 + lrow) * LDS_STRIDE + k0];
            bf16x8 b0 = *(const bf16x8*)&Wt[(wc * 32 +      lrow) * LDS_STRIDE + k0];
            bf16x8 b1 = *(const bf16x8*)&Wt[(wc * 32 + 16 + lrow) * LDS_STRIDE + k0];
            acc[0][0] = __builtin_amdgcn_mfma_f32_16x16x32_bf16(a0, b0, acc[0][0], 0, 0, 0);
            acc[0][1] = __builtin_amdgcn_mfma_f32_16x16x32_bf16(a0, b1, acc[0][1], 0, 0, 0);
            acc[1][0] = __builtin_amdgcn_mfma_f32_16x16x32_bf16(a1, b0, acc[1][0], 0, 0, 0);
            acc[1][1] = __builtin_amdgcn_mfma_f32_16x16x32_bf16(a1, b1, acc[1][1], 0, 0, 0);
        }
        __syncthreads();
    }

    // Epilogue: C/D layout col=lane&15, row=quad*4+reg (verified m89/m91).
    #pragma unroll
    for (int fm = 0; fm < 2; ++fm) {
        #pragma unroll
        for (int fn = 0; fn < 2; ++fn) {
            const int c = bn + wc * 32 + fn * 16 + lrow;
            const float bv = bias ? bias[c] : 0.0f;
            #pragma unroll
            for (int reg = 0; reg < 4; ++reg) {
                const int r = bm + wr * 32 + fm * 16 + quad * 4 + reg;
                float v = acc[fm][fn][reg] + bv;
                if (relu) v = fmaxf(v, 0.0f);
                C[(size_t)r * N + c] = v;
            }
        }
    }
}

// out[b,c] = sum_i f0[b,i] * t[b, i*2+c] + b_out[c]; one block per row b.
__global__ __launch_bounds__(256) void kron_reduce(
    const float* __restrict__ f0, const float* __restrict__ t,
    const float* __restrict__ b_out, float* __restrict__ out)
{
    const int b = blockIdx.x;
    const int i = threadIdx.x;             // 0..255
    const float  v  = f0[(size_t)b * 256 + i];
    const float2 tv = ((const float2*)(t + (size_t)b * 512))[i];
    float p0 = v * tv.x;
    float p1 = v * tv.y;

    #pragma unroll
    for (int off = 32; off > 0; off >>= 1) {
        p0 += __shfl_down(p0, off);
        p1 += __shfl_down(p1, off);
    }
    __shared__ float s0[4], s1[4];
    const int wave = i >> 6;
    if ((i & 63) == 0) { s0[wave] = p0; s1[wave] = p1; }
    __syncthreads();
    if (i == 0) {
        out[(size_t)b * 2 + 0] = s0[0] + s0[1] + s0[2] + s0[3] + b_out[0];
        out[(size_t)b * 2 + 1] = s1[0] + s1[1] + s1[2] + s1[3] + b_out[1];
    }
}

extern "C" void kernel_launch(void* const* d_in, const int* in_sizes, int n_in,
                              void* d_out, int out_size, void* d_ws, size_t ws_size,
                              hipStream_t stream) {
    const float* x0     = (const float*)d_in[0];
    const float* x1     = (const float*)d_in[1];
    const float* W_feat = (const float*)d_in[2];
    const float* b_feat = (const float*)d_in[3];
    const float* W_br0  = (const float*)d_in[4];
    const float* b_br0  = (const float*)d_in[5];
    const float* W_br1  = (const float*)d_in[6];
    const float* b_br1  = (const float*)d_in[7];
    const float* W_out  = (const float*)d_in[8];
    const float* b_out  = (const float*)d_in[9];
    float* out = (float*)d_out;

    const int B = 2048, HID = 512, FEAT = 256;

    float* ws = (float*)d_ws;
    float* h0 = ws;                       // 2048*512
    float* h1 = h0 + (size_t)B * HID;     // 2048*512
    float* f0 = h1 + (size_t)B * HID;     // 2048*256
    float* f1 = f0 + (size_t)B * FEAT;    // 2048*256
    float* t  = f1 + (size_t)B * FEAT;    // 2048*512
    // total: 16 MiB of d_ws

    dim3 blk(256);

    // h_b = relu(x_b @ W_feat + b_feat)   [2048,512], K=1024
    gemm_mfma<<<dim3(512 / BN, B / BM, 2), blk, 0, stream>>>(
        x0, x1, W_feat, W_feat, b_feat, b_feat, h0, h1, B, 512, 1024, 1);

    // f_b = h_b @ W_br_b + b_br_b         [2048,256], K=512
    gemm_mfma<<<dim3(256 / BN, B / BM, 2), blk, 0, stream>>>(
        h0, h1, W_br0, W_br1, b_br0, b_br1, f0, f1, B, 256, 512, 0);

    // t = f1 @ Wr (W_out viewed as [256,512] row-major)  K=256
    gemm_mfma<<<dim3(512 / BN, B / BM, 1), blk, 0, stream>>>(
        f1, f1, W_out, W_out, nullptr, nullptr, t, t, B, 512, 256, 0);

    // out[b,c] = sum_i f0[b,i]*t[b,i*2+c] + b_out[c]
    kron_reduce<<<dim3(B), blk, 0, stream>>>(f0, t, b_out, out);
}

// Round 3
// 118.812 us; speedup vs baseline: 2.3224x; 1.3177x over previous
//
#include <hip/hip_runtime.h>
#include <hip/hip_bf16.h>

// Problem: B=2048, IN_DIM=1024, HID=512, FEAT=256, all fp32.
//   h_b = relu(x_b @ W_feat + b_feat); f_b = h_b @ W_br_b + b_br_b
//   out[b,c] = sum_{j,i} f1[j] f0[i] W_out[j*256+i, c] + b_out[c]
// Kron trick: W_out viewed as Wr[256,512]: t = f1 @ Wr;
//   out[b,c] = sum_i f0[b,i] * t[b, i*2+c] + b_out[c]
//
// R3: pre-convert inputs/weights to bf16 (weights transposed to [N][K]),
// bf16 intermediates, register-prefetch pipelined MFMA GEMM.

typedef __attribute__((ext_vector_type(8))) short bf16x8;  // 8 bf16 = 4 VGPRs
typedef __attribute__((ext_vector_type(4))) float f32x4;
typedef unsigned short u16;

#define LDS_STRIDE 72   // 64 + 8 pad: row stride 144 B -> 2-way bank alias (free, m136)

__device__ __forceinline__ u16 f2bf(float f) {
    unsigned int u = __float_as_uint(f);
    return (u16)((u + 0x7FFFu + ((u >> 16) & 1u)) >> 16);   // RNE
}
__device__ __forceinline__ float bf2f(u16 h) {
    return __uint_as_float(((unsigned int)h) << 16);
}

// x0/x1 fp32 -> bf16, straight copy. n multiple of 8.
__global__ __launch_bounds__(256) void convert_x(
    const float* __restrict__ s0, u16* __restrict__ d0,
    const float* __restrict__ s1, u16* __restrict__ d1, int n)
{
    const float* s = blockIdx.y ? s1 : s0;
    u16* d = blockIdx.y ? d1 : d0;
    int idx = (blockIdx.x * 256 + threadIdx.x) * 8;
    if (idx >= n) return;
    float4 a = *(const float4*)&s[idx];
    float4 b = *(const float4*)&s[idx + 4];
    ushort4 ha; ha.x = f2bf(a.x); ha.y = f2bf(a.y); ha.z = f2bf(a.z); ha.w = f2bf(a.w);
    ushort4 hb; hb.x = f2bf(b.x); hb.y = f2bf(b.y); hb.z = f2bf(b.z); hb.w = f2bf(b.w);
    *(ushort4*)&d[idx] = ha;
    *(ushort4*)&d[idx + 4] = hb;
}

// 4 weight matrices: src[K][N] fp32 row-major -> dst[N][K] bf16 (transposed).
// dst[local] with local = n*K + k; K = 1<<lk. Writes coalesced 2B; reads cached.
__global__ __launch_bounds__(256) void transpose_convert(
    const float* s0, u16* d0, int lk0, int N0,
    const float* s1, u16* d1, int lk1, int N1,
    const float* s2, u16* d2, int lk2, int N2,
    const float* s3, u16* d3, int lk3, int N3,
    int c0, int c1, int c2, int c3)
{
    int gid = blockIdx.x * 256 + threadIdx.x;
    const float* s; u16* d; int lk, N, local;
    if (gid < c0)      { s = s0; d = d0; lk = lk0; N = N0; local = gid; }
    else if (gid < c1) { s = s1; d = d1; lk = lk1; N = N1; local = gid - c0; }
    else if (gid < c2) { s = s2; d = d2; lk = lk2; N = N2; local = gid - c1; }
    else if (gid < c3) { s = s3; d = d3; lk = lk3; N = N3; local = gid - c2; }
    else return;
    int k = local & ((1 << lk) - 1);
    int n = local >> lk;
    d[local] = f2bf(s[(size_t)k * N + n]);
}

// C = [relu](A @ W + bias). A: [M,K] bf16 row-major. WT: [N,K] bf16 (n-major).
// C: bf16 or fp32 per out_bf16. blockIdx.z picks branch pointer set.
// 64x64 tile, BK=64, 4 waves each 32x32 (2x2 frags of 16x16x32).
// Register-prefetch pipeline: issue tile k+1 global loads before computing
// tile k from LDS -> vmcnt drain lands after compute (latency overlapped).
__global__ __launch_bounds__(256) void gemm_bf16(
    const u16* __restrict__ A0, const u16* __restrict__ A1,
    const u16* __restrict__ WT0, const u16* __restrict__ WT1,
    const float* __restrict__ bias0, const float* __restrict__ bias1,
    void* __restrict__ C0v, void* __restrict__ C1v,
    int M, int N, int K, int relu, int out_bf16)
{
    const u16* A    = blockIdx.z ? A1 : A0;
    const u16* WT   = blockIdx.z ? WT1 : WT0;
    const float* bias = blockIdx.z ? bias1 : bias0;
    void* Cv        = blockIdx.z ? C1v : C0v;

    __shared__ __align__(16) u16 As[64 * LDS_STRIDE]; // [m][k]
    __shared__ __align__(16) u16 Ws[64 * LDS_STRIDE]; // [n][k]

    const int tid  = threadIdx.x;
    const int lane = tid & 63;
    const int wave = tid >> 6;
    const int wr   = wave >> 1;
    const int wc   = wave & 1;
    const int lrow = lane & 15;
    const int quad = lane >> 4;

    const int bm = blockIdx.y * 64;
    const int bn = blockIdx.x * 64;

    // staging: 512 chunks of 8 bf16 per tile; thread covers chunk tid and tid+256
    const int r0 = tid >> 3;            // rows 0..31
    const int r1 = r0 + 32;             // rows 32..63
    const int k8 = (tid & 7) * 8;

    const u16* pA0 = A  + (size_t)(bm + r0) * K + k8;
    const u16* pA1 = A  + (size_t)(bm + r1) * K + k8;
    const u16* pW0 = WT + (size_t)(bn + r0) * K + k8;
    const u16* pW1 = WT + (size_t)(bn + r1) * K + k8;

    f32x4 acc[2][2] = {};

    int4 ra0 = *(const int4*)pA0;
    int4 ra1 = *(const int4*)pA1;
    int4 rw0 = *(const int4*)pW0;
    int4 rw1 = *(const int4*)pW1;
    *(int4*)&As[r0 * LDS_STRIDE + k8] = ra0;
    *(int4*)&As[r1 * LDS_STRIDE + k8] = ra1;
    *(int4*)&Ws[r0 * LDS_STRIDE + k8] = rw0;
    *(int4*)&Ws[r1 * LDS_STRIDE + k8] = rw1;
    __syncthreads();

    for (int kk = 0; kk < K; kk += 64) {
        const int nxt = kk + 64;
        if (nxt < K) {          // prefetch next tile into registers
            ra0 = *(const int4*)(pA0 + nxt);
            ra1 = *(const int4*)(pA1 + nxt);
            rw0 = *(const int4*)(pW0 + nxt);
            rw1 = *(const int4*)(pW1 + nxt);
        }
        #pragma unroll
        for (int ks = 0; ks < 2; ++ks) {
            const int k0 = ks * 32 + quad * 8;
            bf16x8 a0 = *(const bf16x8*)&As[(wr * 32 +      lrow) * LDS_STRIDE + k0];
            bf16x8 a1 = *(const bf16x8*)&As[(wr * 32 + 16 + lrow) * LDS_STRIDE + k0];
            bf16x8 b0 = *(const bf16x8*)&Ws[(wc * 32 +      lrow) * LDS_STRIDE + k0];
            bf16x8 b1 = *(const bf16x8*)&Ws[(wc * 32 + 16 + lrow) * LDS_STRIDE + k0];
            acc[0][0] = __builtin_amdgcn_mfma_f32_16x16x32_bf16(a0, b0, acc[0][0], 0, 0, 0);
            acc[0][1] = __builtin_amdgcn_mfma_f32_16x16x32_bf16(a0, b1, acc[0][1], 0, 0, 0);
            acc[1][0] = __builtin_amdgcn_mfma_f32_16x16x32_bf16(a1, b0, acc[1][0], 0, 0, 0);
            acc[1][1] = __builtin_amdgcn_mfma_f32_16x16x32_bf16(a1, b1, acc[1][1], 0, 0, 0);
        }
        if (nxt < K) {
            __syncthreads();
            *(int4*)&As[r0 * LDS_STRIDE + k8] = ra0;
            *(int4*)&As[r1 * LDS_STRIDE + k8] = ra1;
            *(int4*)&Ws[r0 * LDS_STRIDE + k8] = rw0;
            *(int4*)&Ws[r1 * LDS_STRIDE + k8] = rw1;
            __syncthreads();
        }
    }

    // C/D layout: col=lane&15, row=quad*4+reg (verified m89/m91).
    #pragma unroll
    for (int fm = 0; fm < 2; ++fm) {
        #pragma unroll
        for (int fn = 0; fn < 2; ++fn) {
            const int c = bn + wc * 32 + fn * 16 + lrow;
            const float bv = bias ? bias[c] : 0.0f;
            #pragma unroll
            for (int reg = 0; reg < 4; ++reg) {
                const int r = bm + wr * 32 + fm * 16 + quad * 4 + reg;
                float v = acc[fm][fn][reg] + bv;
                if (relu) v = fmaxf(v, 0.0f);
                if (out_bf16) ((u16*)Cv)[(size_t)r * N + c] = f2bf(v);
                else          ((float*)Cv)[(size_t)r * N + c] = v;
            }
        }
    }
}

// out[b,c] = sum_i f0[b,i] * t[b, i*2+c] + b_out[c]; one block per row b.
__global__ __launch_bounds__(256) void kron_reduce(
    const u16* __restrict__ f0, const float* __restrict__ t,
    const float* __restrict__ b_out, float* __restrict__ out)
{
    const int b = blockIdx.x;
    const int i = threadIdx.x;
    const float  v  = bf2f(f0[(size_t)b * 256 + i]);
    const float2 tv = ((const float2*)(t + (size_t)b * 512))[i];
    float p0 = v * tv.x;
    float p1 = v * tv.y;

    #pragma unroll
    for (int off = 32; off > 0; off >>= 1) {
        p0 += __shfl_down(p0, off);
        p1 += __shfl_down(p1, off);
    }
    __shared__ float s0[4], s1[4];
    const int wave = i >> 6;
    if ((i & 63) == 0) { s0[wave] = p0; s1[wave] = p1; }
    __syncthreads();
    if (i == 0) {
        out[(size_t)b * 2 + 0] = s0[0] + s0[1] + s0[2] + s0[3] + b_out[0];
        out[(size_t)b * 2 + 1] = s1[0] + s1[1] + s1[2] + s1[3] + b_out[1];
    }
}

extern "C" void kernel_launch(void* const* d_in, const int* in_sizes, int n_in,
                              void* d_out, int out_size, void* d_ws, size_t ws_size,
                              hipStream_t stream) {
    const float* x0     = (const float*)d_in[0];
    const float* x1     = (const float*)d_in[1];
    const float* W_feat = (const float*)d_in[2];
    const float* b_feat = (const float*)d_in[3];
    const float* W_br0  = (const float*)d_in[4];
    const float* b_br0  = (const float*)d_in[5];
    const float* W_br1  = (const float*)d_in[6];
    const float* b_br1  = (const float*)d_in[7];
    const float* W_out  = (const float*)d_in[8];
    const float* b_out  = (const float*)d_in[9];
    float* out = (float*)d_out;

    const int B = 2048, IN = 1024, HID = 512, FEAT = 256;

    u16* xb0  = (u16*)d_ws;                 // [2048][1024]
    u16* xb1  = xb0  + (size_t)B * IN;
    u16* WfT  = xb1  + (size_t)B * IN;      // [512][1024]
    u16* Wb0T = WfT  + (size_t)HID * IN;    // [256][512]
    u16* Wb1T = Wb0T + (size_t)FEAT * HID;
    u16* WrT  = Wb1T + (size_t)FEAT * HID;  // [512][256]
    u16* h0   = WrT  + (size_t)HID * FEAT;  // [2048][512] bf16
    u16* h1   = h0   + (size_t)B * HID;
    u16* f0   = h1   + (size_t)B * HID;     // [2048][256] bf16
    u16* f1   = f0   + (size_t)B * FEAT;
    float* t  = (float*)(f1 + (size_t)B * FEAT);  // [2048][512] fp32
    // total ~20.5 MiB of d_ws

    dim3 blk(256);

    // x -> bf16
    convert_x<<<dim3((B * IN / 8 + 255) / 256, 2), blk, 0, stream>>>(
        x0, xb0, x1, xb1, B * IN);

    // weights -> bf16 transposed [N][K]
    const int c0 = HID * IN;                 // 524288  (W_feat: K=1024, N=512)
    const int c1 = c0 + FEAT * HID;          // +131072 (W_br0:  K=512,  N=256)
    const int c2 = c1 + FEAT * HID;          // +131072 (W_br1)
    const int c3 = c2 + HID * FEAT;          // +131072 (Wr:     K=256,  N=512)
    transpose_convert<<<dim3((c3 + 255) / 256), blk, 0, stream>>>(
        W_feat, WfT,  10, 512,
        W_br0,  Wb0T,  9, 256,
        W_br1,  Wb1T,  9, 256,
        W_out,  WrT,   8, 512,
        c0, c1, c2, c3);

    // h_b = relu(x_b @ W_feat + b_feat)   [2048,512] bf16, K=1024
    gemm_bf16<<<dim3(512 / 64, B / 64, 2), blk, 0, stream>>>(
        xb0, xb1, WfT, WfT, b_feat, b_feat, h0, h1, B, 512, 1024, 1, 1);

    // f_b = h_b @ W_br_b + b_br_b         [2048,256] bf16, K=512
    gemm_bf16<<<dim3(256 / 64, B / 64, 2), blk, 0, stream>>>(
        h0, h1, Wb0T, Wb1T, b_br0, b_br1, f0, f1, B, 256, 512, 0, 1);

    // t = f1 @ Wr                          [2048,512] fp32, K=256
    gemm_bf16<<<dim3(512 / 64, B / 64, 1), blk, 0, stream>>>(
        f1, f1, WrT, WrT, nullptr, nullptr, t, t, B, 512, 256, 0, 0);

    // out[b,c] = sum_i f0[b,i]*t[b,i*2+c] + b_out[c]
    kron_reduce<<<dim3(B), blk, 0, stream>>>(f0, t, b_out, out);
}